// Round 10
// baseline (179.839 us; speedup 1.0000x reference)
//
#include <hip/hip_runtime.h>

#define N_NODES 50000
#define N_EDGES 800000
#define FEAT    128

#define NRANGE  8
#define NSLICE  32
#define NBLK    (NRANGE * NSLICE)      // 256 blocks, 1/CU (co-resident)
#define RN_REAL (N_NODES / NRANGE)     // 6250 nodes per range
#define RNP     6400                   // padded LDS/partial stride (25.6 KB)
#define RGROUPS (RNP / 4)              // 1600 float4 groups
#define SLICE_Q (N_EDGES / NSLICE / 4) // 6250 quads per slice
#define TB      1024
#define NPB     ((N_NODES + NBLK - 1) / NBLK)  // 196 nodes per block
#define FSTRIDE 32                     // u32 stride between flags = 128 B/line

// ws: partial[NBLK*RNP] f32 | li0[N_NODES] f32 | flags[4*NBLK*FSTRIDE] u32 | sum f32 | ticket u32
#define NFLAGS  (4 * NBLK * FSTRIDE)   // 32768 u32

__global__ void init_ctl(unsigned* __restrict__ flags, float* sum, unsigned* ticket) {
    int i = blockIdx.x * blockDim.x + threadIdx.x;
    if (i < NFLAGS) flags[i] = 0u;
    if (i == 0) { *sum = 0.0f; *ticket = 0u; }
}

// Zero-contention relay grid barrier: every flag line has exactly one
// writer and one poller. Block 0 detects all arrivals (one line per
// thread), then fans out per-block release flags.
__device__ __forceinline__ void grid_barrier(unsigned* arrive, unsigned* release) {
    __syncthreads();
    const int bid = blockIdx.x;
    if (bid == 0) {
        if (threadIdx.x > 0 && threadIdx.x < NBLK) {
            while (__hip_atomic_load(&arrive[threadIdx.x * FSTRIDE],
                    __ATOMIC_ACQUIRE, __HIP_MEMORY_SCOPE_AGENT) == 0u)
                __builtin_amdgcn_s_sleep(8);
        }
        __syncthreads();
        __threadfence();
        if (threadIdx.x > 0 && threadIdx.x < NBLK)
            __hip_atomic_store(&release[threadIdx.x * FSTRIDE], 1u,
                               __ATOMIC_RELEASE, __HIP_MEMORY_SCOPE_AGENT);
    } else {
        if (threadIdx.x == 0) {
            __threadfence();
            __hip_atomic_store(&arrive[bid * FSTRIDE], 1u,
                               __ATOMIC_RELEASE, __HIP_MEMORY_SCOPE_AGENT);
            while (__hip_atomic_load(&release[bid * FSTRIDE],
                    __ATOMIC_ACQUIRE, __HIP_MEMORY_SCOPE_AGENT) == 0u)
                __builtin_amdgcn_s_sleep(8);
            __threadfence();
        }
        __syncthreads();
    }
}

__global__ __launch_bounds__(TB) void fused(
        const float* __restrict__ li,
        const float* __restrict__ w,
        const int* __restrict__ row,
        const int* __restrict__ col,
        float* __restrict__ partial,
        float* __restrict__ li0,
        unsigned* __restrict__ flags,
        float* sum, unsigned* ticket,
        float* __restrict__ out) {
    __shared__ float accl[RNP];                    // 25.6 KB
    __shared__ float smr[TB / 64];
    const int bid = blockIdx.x;
    const int s  = bid & (NSLICE - 1);             // siblings share XCD (b%8==s%8)
    const int r  = bid >> 5;
    const int lo = r * RN_REAL;

    unsigned* arrA = flags;
    unsigned* relA = flags + NBLK * FSTRIDE;
    unsigned* arrB = flags + 2 * NBLK * FSTRIDE;
    unsigned* relB = flags + 3 * NBLK * FSTRIDE;

    // ---- phase 0: pack li column 0 (196 nodes/block) + zero LDS ----
    {
        int n = bid * NPB + threadIdx.x;
        if (threadIdx.x < NPB && n < N_NODES)
            li0[n] = li[(size_t)n * FEAT];
    }
    float4* az = (float4*)accl;
    for (int i = threadIdx.x; i < RGROUPS; i += TB)
        az[i] = make_float4(0.f, 0.f, 0.f, 0.f);

    grid_barrier(arrA, relA);                      // li0 complete everywhere

    // ---- phase 1: stream slice, LDS-atomic accumulate into range ----
    const float4* wq = (const float4*)w   + (size_t)s * SLICE_Q;
    const int4*   rq = (const int4*)row   + (size_t)s * SLICE_Q;
    const int4*   cq = (const int4*)col   + (size_t)s * SLICE_Q;

    for (int q = threadIdx.x; q < SLICE_Q; q += TB) {
        float4 wv = wq[q];
        int4   rv = rq[q];
        int4   cv = cq[q];
        int a;
        a = rv.x - lo; if ((unsigned)a < RN_REAL) atomicAdd(&accl[a], wv.x * li0[cv.x]);
        a = rv.y - lo; if ((unsigned)a < RN_REAL) atomicAdd(&accl[a], wv.y * li0[cv.y]);
        a = rv.z - lo; if ((unsigned)a < RN_REAL) atomicAdd(&accl[a], wv.z * li0[cv.z]);
        a = rv.w - lo; if ((unsigned)a < RN_REAL) atomicAdd(&accl[a], wv.w * li0[cv.w]);
    }
    __syncthreads();

    // ---- phase 2: flush partial ----
    float4* pdst = (float4*)(partial + (size_t)bid * RNP);
    for (int i = threadIdx.x; i < RGROUPS; i += TB) pdst[i] = az[i];

    grid_barrier(arrB, relB);                      // partials complete everywhere

    // ---- phase 3: per-node sum of 32 slice-partials, relu, global sum ----
    float local = 0.0f;
    int n = bid * NPB + threadIdx.x;
    if (threadIdx.x < NPB && n < N_NODES) {
        int rr = n / RN_REAL;
        int nl = n - rr * RN_REAL;
        const float* base = partial + (size_t)(rr * NSLICE) * RNP + nl;
        float a0 = 0.f, a1 = 0.f, a2 = 0.f, a3 = 0.f;
        #pragma unroll
        for (int b = 0; b < NSLICE; b += 4) {
            a0 += base[(size_t)(b + 0) * RNP];
            a1 += base[(size_t)(b + 1) * RNP];
            a2 += base[(size_t)(b + 2) * RNP];
            a3 += base[(size_t)(b + 3) * RNP];
        }
        local = fmaxf(a0 + a1 + a2 + a3, 0.f);
    }
    #pragma unroll
    for (int off = 32; off > 0; off >>= 1)
        local += __shfl_down(local, off, 64);
    if ((threadIdx.x & 63) == 0) smr[threadIdx.x >> 6] = local;
    __syncthreads();
    if (threadIdx.x == 0) {
        float t = 0.f;
        #pragma unroll
        for (int i = 0; i < TB / 64; ++i) t += smr[i];
        atomicAdd(sum, t);
        __threadfence();
        unsigned old = atomicAdd(ticket, 1u);
        if (old == NBLK - 1) {                     // last block finalizes
            float v = __hip_atomic_load(sum, __ATOMIC_RELAXED, __HIP_MEMORY_SCOPE_AGENT);
            out[0] = 1.0f / (1.0f + expf(-v));
        }
    }
}

// ---------------- fallback (tiny ws): global atomics ----------------

__global__ void zero_acc(float* __restrict__ acc, float* sum, unsigned* ticket) {
    int i = blockIdx.x * blockDim.x + threadIdx.x;
    if (i < N_NODES) acc[i] = 0.0f;
    if (i == 0) { *sum = 0.0f; *ticket = 0u; }
}

__global__ void edge_scatter4(const float* __restrict__ li,
                              const float* __restrict__ w,
                              const int* __restrict__ row,
                              const int* __restrict__ col,
                              float* __restrict__ acc) {
    int t = blockIdx.x * blockDim.x + threadIdx.x;
    if (t < N_EDGES / 4) {
        float4 wv = ((const float4*)w)[t];
        int4   rv = ((const int4*)row)[t];
        int4   cv = ((const int4*)col)[t];
        atomicAdd(&acc[rv.x], wv.x * li[(size_t)cv.x * FEAT]);
        atomicAdd(&acc[rv.y], wv.y * li[(size_t)cv.y * FEAT]);
        atomicAdd(&acc[rv.z], wv.z * li[(size_t)cv.z * FEAT]);
        atomicAdd(&acc[rv.w], wv.w * li[(size_t)cv.w * FEAT]);
    }
}

__global__ void relu_sum_fin(const float* __restrict__ acc,
                             float* __restrict__ sum,
                             unsigned* __restrict__ ticket,
                             float* __restrict__ out) {
    float local = 0.0f;
    for (int i = blockIdx.x * blockDim.x + threadIdx.x; i < N_NODES / 4;
         i += gridDim.x * blockDim.x) {
        float4 a = ((const float4*)acc)[i];
        local += fmaxf(a.x, 0.f) + fmaxf(a.y, 0.f) +
                 fmaxf(a.z, 0.f) + fmaxf(a.w, 0.f);
    }
    #pragma unroll
    for (int off = 32; off > 0; off >>= 1)
        local += __shfl_down(local, off, 64);
    __shared__ float sm[4];
    if ((threadIdx.x & 63) == 0) sm[threadIdx.x >> 6] = local;
    __syncthreads();
    if (threadIdx.x == 0) {
        atomicAdd(sum, sm[0] + sm[1] + sm[2] + sm[3]);
        __threadfence();
        unsigned old = atomicAdd(ticket, 1u);
        if (old == gridDim.x - 1) {
            float v = __hip_atomic_load(sum, __ATOMIC_RELAXED, __HIP_MEMORY_SCOPE_AGENT);
            out[0] = 1.0f / (1.0f + expf(-v));
        }
    }
}

extern "C" void kernel_launch(void* const* d_in, const int* in_sizes, int n_in,
                              void* d_out, int out_size, void* d_ws, size_t ws_size,
                              hipStream_t stream) {
    const float* li  = (const float*)d_in[0];
    const float* w   = (const float*)d_in[1];
    const int*   row = (const int*)d_in[2];
    const int*   col = (const int*)d_in[3];
    float* out = (float*)d_out;

    size_t need = (size_t)NBLK * RNP * 4 + (size_t)N_NODES * 4
                + (size_t)NFLAGS * 4 + 16;

    if (ws_size >= need) {
        float*    partial = (float*)d_ws;
        float*    li0     = partial + (size_t)NBLK * RNP;
        unsigned* flags   = (unsigned*)(li0 + N_NODES);
        float*    sum     = (float*)(flags + NFLAGS);
        unsigned* ticket  = (unsigned*)(sum + 1);

        init_ctl<<<(NFLAGS + TB - 1) / TB, TB, 0, stream>>>(flags, sum, ticket);
        fused<<<NBLK, TB, 0, stream>>>(li, w, row, col, partial, li0,
                                       flags, sum, ticket, out);
    } else {
        float*    acc    = (float*)d_ws;
        float*    sum    = acc + N_NODES;
        unsigned* ticket = (unsigned*)(sum + 1);

        zero_acc<<<(N_NODES + 255) / 256, 256, 0, stream>>>(acc, sum, ticket);
        edge_scatter4<<<(N_EDGES / 4 + 255) / 256, 256, 0, stream>>>(li, w, row, col, acc);
        relu_sum_fin<<<49, 256, 0, stream>>>(acc, sum, ticket, out);
    }
}

// Round 11
// 94.298 us; speedup vs baseline: 1.9071x; 1.9071x over previous
//
#include <hip/hip_runtime.h>
#include <hip/hip_cooperative_groups.h>

namespace cg = cooperative_groups;

#define N_NODES 50000
#define N_EDGES 800000
#define FEAT    128

#define NRANGE  8
#define NSLICE  32
#define NBLK    (NRANGE * NSLICE)      // 256 blocks, co-resident (1/CU)
#define RN_REAL (N_NODES / NRANGE)     // 6250 nodes per range
#define RNP     6400                   // padded LDS/partial stride (25.6 KB)
#define RGROUPS (RNP / 4)              // 1600 float4 groups
#define SLICE_Q (N_EDGES / NSLICE / 4) // 6250 quads per slice
#define TB      1024
#define NPB     ((N_NODES + NBLK - 1) / NBLK)  // 196 nodes per block

// ws layout: partial[NBLK*RNP] f32 | li0[N_NODES] f32 | sum f32 | ticket u32

__global__ __launch_bounds__(TB) void fused_coop(
        const float* __restrict__ li,
        const float* __restrict__ w,
        const int* __restrict__ row,
        const int* __restrict__ col,
        float* __restrict__ partial,
        float* __restrict__ li0,
        float* sum, unsigned* ticket,
        float* __restrict__ out) {
    cg::grid_group grid = cg::this_grid();
    __shared__ float accl[RNP];                    // 25.6 KB
    __shared__ float smr[TB / 64];
    const int bid = blockIdx.x;
    const int s  = bid & (NSLICE - 1);             // bid%8 == s%8 -> siblings on same XCD
    const int r  = bid >> 5;
    const int lo = r * RN_REAL;

    // ---- phase 0: pack li column 0 (196 nodes/block), init ctl, zero LDS ----
    {
        int n = bid * NPB + threadIdx.x;
        if (threadIdx.x < NPB && n < N_NODES)
            li0[n] = li[(size_t)n * FEAT];
        if (bid == 0 && threadIdx.x == 0) { *sum = 0.0f; *ticket = 0u; }
    }
    float4* az = (float4*)accl;
    for (int i = threadIdx.x; i < RGROUPS; i += TB)
        az[i] = make_float4(0.f, 0.f, 0.f, 0.f);

    grid.sync();                                   // li0 + ctl visible everywhere

    // ---- phase 1: stream slice, filter to range, LDS-atomic accumulate ----
    const float4* wq = (const float4*)w   + (size_t)s * SLICE_Q;
    const int4*   rq = (const int4*)row   + (size_t)s * SLICE_Q;
    const int4*   cq = (const int4*)col   + (size_t)s * SLICE_Q;

    for (int q = threadIdx.x; q < SLICE_Q; q += TB) {
        float4 wv = wq[q];
        int4   rv = rq[q];
        int4   cv = cq[q];
        int a;
        a = rv.x - lo; if ((unsigned)a < RN_REAL) atomicAdd(&accl[a], wv.x * li0[cv.x]);
        a = rv.y - lo; if ((unsigned)a < RN_REAL) atomicAdd(&accl[a], wv.y * li0[cv.y]);
        a = rv.z - lo; if ((unsigned)a < RN_REAL) atomicAdd(&accl[a], wv.z * li0[cv.z]);
        a = rv.w - lo; if ((unsigned)a < RN_REAL) atomicAdd(&accl[a], wv.w * li0[cv.w]);
    }
    __syncthreads();

    // ---- phase 2: flush 25.6 KB partial ----
    float4* pdst = (float4*)(partial + (size_t)bid * RNP);
    for (int i = threadIdx.x; i < RGROUPS; i += TB) pdst[i] = az[i];

    grid.sync();                                   // partials visible everywhere

    // ---- phase 3: per-node sum of 32 slice-partials, relu, global sum ----
    float local = 0.0f;
    int n = bid * NPB + threadIdx.x;
    if (threadIdx.x < NPB && n < N_NODES) {
        int rr = n / RN_REAL;
        int nl = n - rr * RN_REAL;
        const float* base = partial + (size_t)(rr * NSLICE) * RNP + nl;
        float a0 = 0.f, a1 = 0.f, a2 = 0.f, a3 = 0.f;
        #pragma unroll
        for (int b = 0; b < NSLICE; b += 4) {
            a0 += base[(size_t)(b + 0) * RNP];
            a1 += base[(size_t)(b + 1) * RNP];
            a2 += base[(size_t)(b + 2) * RNP];
            a3 += base[(size_t)(b + 3) * RNP];
        }
        local = fmaxf(a0 + a1 + a2 + a3, 0.f);
    }
    #pragma unroll
    for (int off = 32; off > 0; off >>= 1)
        local += __shfl_down(local, off, 64);
    if ((threadIdx.x & 63) == 0) smr[threadIdx.x >> 6] = local;
    __syncthreads();
    if (threadIdx.x == 0) {
        float t = 0.f;
        #pragma unroll
        for (int i = 0; i < TB / 64; ++i) t += smr[i];
        atomicAdd(sum, t);
        __threadfence();
        unsigned old = atomicAdd(ticket, 1u);
        if (old == NBLK - 1) {                     // last block finalizes
            float v = __hip_atomic_load(sum, __ATOMIC_RELAXED, __HIP_MEMORY_SCOPE_AGENT);
            out[0] = 1.0f / (1.0f + expf(-v));
        }
    }
}

// ---------------- fallback (tiny ws): global atomics ----------------

__global__ void zero_acc(float* __restrict__ acc, float* sum, unsigned* ticket) {
    int i = blockIdx.x * blockDim.x + threadIdx.x;
    if (i < N_NODES) acc[i] = 0.0f;
    if (i == 0) { *sum = 0.0f; *ticket = 0u; }
}

__global__ void edge_scatter4(const float* __restrict__ li,
                              const float* __restrict__ w,
                              const int* __restrict__ row,
                              const int* __restrict__ col,
                              float* __restrict__ acc) {
    int t = blockIdx.x * blockDim.x + threadIdx.x;
    if (t < N_EDGES / 4) {
        float4 wv = ((const float4*)w)[t];
        int4   rv = ((const int4*)row)[t];
        int4   cv = ((const int4*)col)[t];
        atomicAdd(&acc[rv.x], wv.x * li[(size_t)cv.x * FEAT]);
        atomicAdd(&acc[rv.y], wv.y * li[(size_t)cv.y * FEAT]);
        atomicAdd(&acc[rv.z], wv.z * li[(size_t)cv.z * FEAT]);
        atomicAdd(&acc[rv.w], wv.w * li[(size_t)cv.w * FEAT]);
    }
}

__global__ void relu_sum_fin(const float* __restrict__ acc,
                             float* __restrict__ sum,
                             unsigned* __restrict__ ticket,
                             float* __restrict__ out) {
    float local = 0.0f;
    for (int i = blockIdx.x * blockDim.x + threadIdx.x; i < N_NODES / 4;
         i += gridDim.x * blockDim.x) {
        float4 a = ((const float4*)acc)[i];
        local += fmaxf(a.x, 0.f) + fmaxf(a.y, 0.f) +
                 fmaxf(a.z, 0.f) + fmaxf(a.w, 0.f);
    }
    #pragma unroll
    for (int off = 32; off > 0; off >>= 1)
        local += __shfl_down(local, off, 64);
    __shared__ float sm[4];
    if ((threadIdx.x & 63) == 0) sm[threadIdx.x >> 6] = local;
    __syncthreads();
    if (threadIdx.x == 0) {
        atomicAdd(sum, sm[0] + sm[1] + sm[2] + sm[3]);
        __threadfence();
        unsigned old = atomicAdd(ticket, 1u);
        if (old == gridDim.x - 1) {
            float v = __hip_atomic_load(sum, __ATOMIC_RELAXED, __HIP_MEMORY_SCOPE_AGENT);
            out[0] = 1.0f / (1.0f + expf(-v));
        }
    }
}

extern "C" void kernel_launch(void* const* d_in, const int* in_sizes, int n_in,
                              void* d_out, int out_size, void* d_ws, size_t ws_size,
                              hipStream_t stream) {
    const float* li  = (const float*)d_in[0];
    const float* w   = (const float*)d_in[1];
    const int*   row = (const int*)d_in[2];
    const int*   col = (const int*)d_in[3];
    float* out = (float*)d_out;

    size_t need = (size_t)NBLK * RNP * 4 + (size_t)N_NODES * 4 + 16;

    if (ws_size >= need) {
        float*    partial = (float*)d_ws;
        float*    li0     = partial + (size_t)NBLK * RNP;
        float*    sum     = li0 + N_NODES;
        unsigned* ticket  = (unsigned*)(sum + 1);

        void* args[] = {(void*)&li, (void*)&w, (void*)&row, (void*)&col,
                        (void*)&partial, (void*)&li0, (void*)&sum,
                        (void*)&ticket, (void*)&out};
        hipLaunchCooperativeKernel((void*)fused_coop, dim3(NBLK), dim3(TB),
                                   args, 0, stream);
    } else {
        float*    acc    = (float*)d_ws;
        float*    sum    = acc + N_NODES;
        unsigned* ticket = (unsigned*)(sum + 1);

        zero_acc<<<(N_NODES + 255) / 256, 256, 0, stream>>>(acc, sum, ticket);
        edge_scatter4<<<(N_EDGES / 4 + 255) / 256, 256, 0, stream>>>(li, w, row, col, acc);
        relu_sum_fin<<<49, 256, 0, stream>>>(acc, sum, ticket, out);
    }
}

// Round 12
// 47.973 us; speedup vs baseline: 3.7487x; 1.9656x over previous
//
#include <hip/hip_runtime.h>

#define N_NODES 50000
#define N_EDGES 800000
#define FEAT    128

#define NRANGE  2
#define NSLICE  128
#define NBLK    (NRANGE * NSLICE)      // 256 blocks, 1/CU
#define RN_REAL (N_NODES / NRANGE)     // 25000 nodes per range
#define RNP     25024                  // padded stride (100096 B LDS)
#define Q_TOTAL (N_EDGES / 4)          // 200000 quads
#define TB      1024

// ws layout: partial[NBLK][RNP] f32 | li0[N_NODES] f32 | sum f32 | ticket u32

__global__ void pack_init(const float* __restrict__ li,
                          float* __restrict__ li0,
                          float* sum, unsigned* ticket) {
    int i = blockIdx.x * blockDim.x + threadIdx.x;
    if (i < N_NODES) li0[i] = li[(size_t)i * FEAT];   // pack feature column 0
    if (i == 0) { *sum = 0.0f; *ticket = 0u; }
}

// accum: block (r,s) streams slice s (uneven bounds), gathers li0 for ALL
// edges unconditionally (col always in-bounds; breaks compare->gather dep),
// filters rows to its half of the node space, LDS-atomic accumulates.
// Siblings s and s+128 share bid%8 -> same XCD -> slice re-read L2-served.
__global__ __launch_bounds__(TB) void range_accum(
        const float* __restrict__ li0,
        const float* __restrict__ w,
        const int* __restrict__ row,
        const int* __restrict__ col,
        float* __restrict__ partial) {
    __shared__ float accl[RNP];                    // ~100 KB
    const int s  = blockIdx.x & (NSLICE - 1);
    const int r  = blockIdx.x >> 7;
    const int lo = r * RN_REAL;

    float4* az = (float4*)accl;
    for (int i = threadIdx.x; i < RNP / 4; i += TB)
        az[i] = make_float4(0.f, 0.f, 0.f, 0.f);
    __syncthreads();

    const int q0 = (int)(((long)s       * Q_TOTAL) / NSLICE);
    const int q1 = (int)(((long)(s + 1) * Q_TOTAL) / NSLICE);

    const float4* wq = (const float4*)w;
    const int4*   rq = (const int4*)row;
    const int4*   cq = (const int4*)col;

    for (int q = q0 + threadIdx.x; q < q1; q += TB) {
        float4 wv = wq[q];
        int4   rv = rq[q];
        int4   cv = cq[q];
        // unconditional gathers: col indices always valid, issue immediately
        float g0 = li0[cv.x];
        float g1 = li0[cv.y];
        float g2 = li0[cv.z];
        float g3 = li0[cv.w];
        int a;
        a = rv.x - lo; if ((unsigned)a < RN_REAL) atomicAdd(&accl[a], wv.x * g0);
        a = rv.y - lo; if ((unsigned)a < RN_REAL) atomicAdd(&accl[a], wv.y * g1);
        a = rv.z - lo; if ((unsigned)a < RN_REAL) atomicAdd(&accl[a], wv.z * g2);
        a = rv.w - lo; if ((unsigned)a < RN_REAL) atomicAdd(&accl[a], wv.w * g3);
    }
    __syncthreads();

    float4* pdst = (float4*)(partial + (size_t)blockIdx.x * RNP);
    for (int i = threadIdx.x; i < RN_REAL / 4; i += TB) pdst[i] = az[i];
}

// reduce: one node per thread; sum 128 slice-partials (L3-served), relu,
// block-reduce, ticket-gated sigmoid finalize.
__global__ void reduce_fin(const float* __restrict__ partial,
                           float* __restrict__ sum,
                           unsigned* __restrict__ ticket,
                           float* __restrict__ out) {
    int n = blockIdx.x * blockDim.x + threadIdx.x;
    float local = 0.0f;
    if (n < N_NODES) {
        int rr = (n < RN_REAL) ? 0 : 1;
        int nl = n - rr * RN_REAL;
        const float* base = partial + (size_t)(rr * NSLICE) * RNP + nl;
        float a0 = 0.f, a1 = 0.f, a2 = 0.f, a3 = 0.f;
        #pragma unroll 8
        for (int b = 0; b < NSLICE; b += 4) {
            a0 += base[(size_t)(b + 0) * RNP];
            a1 += base[(size_t)(b + 1) * RNP];
            a2 += base[(size_t)(b + 2) * RNP];
            a3 += base[(size_t)(b + 3) * RNP];
        }
        local = fmaxf(a0 + a1 + a2 + a3, 0.f);
    }
    #pragma unroll
    for (int off = 32; off > 0; off >>= 1)
        local += __shfl_down(local, off, 64);
    __shared__ float sm[4];
    if ((threadIdx.x & 63) == 0) sm[threadIdx.x >> 6] = local;
    __syncthreads();
    if (threadIdx.x == 0) {
        atomicAdd(sum, sm[0] + sm[1] + sm[2] + sm[3]);
        __threadfence();
        unsigned old = atomicAdd(ticket, 1u);
        if (old == gridDim.x - 1) {
            float v = __hip_atomic_load(sum, __ATOMIC_RELAXED, __HIP_MEMORY_SCOPE_AGENT);
            out[0] = 1.0f / (1.0f + expf(-v));
        }
    }
}

// ---------------- fallback (tiny ws): global atomics ----------------

__global__ void zero_acc(float* __restrict__ acc, float* sum, unsigned* ticket) {
    int i = blockIdx.x * blockDim.x + threadIdx.x;
    if (i < N_NODES) acc[i] = 0.0f;
    if (i == 0) { *sum = 0.0f; *ticket = 0u; }
}

__global__ void edge_scatter4(const float* __restrict__ li,
                              const float* __restrict__ w,
                              const int* __restrict__ row,
                              const int* __restrict__ col,
                              float* __restrict__ acc) {
    int t = blockIdx.x * blockDim.x + threadIdx.x;
    if (t < N_EDGES / 4) {
        float4 wv = ((const float4*)w)[t];
        int4   rv = ((const int4*)row)[t];
        int4   cv = ((const int4*)col)[t];
        atomicAdd(&acc[rv.x], wv.x * li[(size_t)cv.x * FEAT]);
        atomicAdd(&acc[rv.y], wv.y * li[(size_t)cv.y * FEAT]);
        atomicAdd(&acc[rv.z], wv.z * li[(size_t)cv.z * FEAT]);
        atomicAdd(&acc[rv.w], wv.w * li[(size_t)cv.w * FEAT]);
    }
}

__global__ void relu_sum_fin(const float* __restrict__ acc,
                             float* __restrict__ sum,
                             unsigned* __restrict__ ticket,
                             float* __restrict__ out) {
    float local = 0.0f;
    for (int i = blockIdx.x * blockDim.x + threadIdx.x; i < N_NODES / 4;
         i += gridDim.x * blockDim.x) {
        float4 a = ((const float4*)acc)[i];
        local += fmaxf(a.x, 0.f) + fmaxf(a.y, 0.f) +
                 fmaxf(a.z, 0.f) + fmaxf(a.w, 0.f);
    }
    #pragma unroll
    for (int off = 32; off > 0; off >>= 1)
        local += __shfl_down(local, off, 64);
    __shared__ float sm[4];
    if ((threadIdx.x & 63) == 0) sm[threadIdx.x >> 6] = local;
    __syncthreads();
    if (threadIdx.x == 0) {
        atomicAdd(sum, sm[0] + sm[1] + sm[2] + sm[3]);
        __threadfence();
        unsigned old = atomicAdd(ticket, 1u);
        if (old == gridDim.x - 1) {
            float v = __hip_atomic_load(sum, __ATOMIC_RELAXED, __HIP_MEMORY_SCOPE_AGENT);
            out[0] = 1.0f / (1.0f + expf(-v));
        }
    }
}

extern "C" void kernel_launch(void* const* d_in, const int* in_sizes, int n_in,
                              void* d_out, int out_size, void* d_ws, size_t ws_size,
                              hipStream_t stream) {
    const float* li  = (const float*)d_in[0];
    const float* w   = (const float*)d_in[1];
    const int*   row = (const int*)d_in[2];
    const int*   col = (const int*)d_in[3];
    float* out = (float*)d_out;

    size_t need = (size_t)NBLK * RNP * 4 + (size_t)N_NODES * 4 + 16;

    if (ws_size >= need) {
        float*    partial = (float*)d_ws;
        float*    li0     = partial + (size_t)NBLK * RNP;
        float*    sum     = li0 + N_NODES;
        unsigned* ticket  = (unsigned*)(sum + 1);

        pack_init<<<(N_NODES + 255) / 256, 256, 0, stream>>>(li, li0, sum, ticket);
        range_accum<<<NBLK, TB, 0, stream>>>(li0, w, row, col, partial);
        reduce_fin<<<(N_NODES + 255) / 256, 256, 0, stream>>>(partial, sum, ticket, out);
    } else {
        float*    acc    = (float*)d_ws;
        float*    sum    = acc + N_NODES;
        unsigned* ticket = (unsigned*)(sum + 1);

        zero_acc<<<(N_NODES + 255) / 256, 256, 0, stream>>>(acc, sum, ticket);
        edge_scatter4<<<(N_EDGES / 4 + 255) / 256, 256, 0, stream>>>(li, w, row, col, acc);
        relu_sum_fin<<<49, 256, 0, stream>>>(acc, sum, ticket, out);
    }
}

// Round 13
// 34.110 us; speedup vs baseline: 5.2723x; 1.4064x over previous
//
#include <hip/hip_runtime.h>

#define N_NODES 50000
#define N_EDGES 800000
#define FEAT    128

#define NRANGE  4
#define NSLICE  64
#define NBLK    (NRANGE * NSLICE)      // 256 blocks, 1/CU
#define RN      (N_NODES / NRANGE)     // 12500 nodes per range -> 50 KB bins
#define SLICE_Q (N_EDGES / NSLICE / 4) // 3125 quads per slice
#define TB      1024

// ws layout: partial[NBLK][RN] f32 | li0h[N_NODES] ushort(bf16) | sum f32 | ticket u32

__device__ __forceinline__ float bf2f(unsigned short h) {
    return __uint_as_float(((unsigned)h) << 16);
}

__global__ void pack_init(const float* __restrict__ li,
                          unsigned short* __restrict__ li0h,
                          float* sum, unsigned* ticket) {
    int i = blockIdx.x * blockDim.x + threadIdx.x;
    if (i < N_NODES) {
        unsigned b = __float_as_uint(li[(size_t)i * FEAT]) + 0x8000u; // rnd bf16
        li0h[i] = (unsigned short)(b >> 16);
    }
    if (i == 0) { *sum = 0.0f; *ticket = 0u; }
}

// accum: copy bf16 li0 into LDS (100 KB), zero 50 KB bins, stream slice,
// gather from LDS, predicated LDS-atomic accumulate, flush partial.
// Siblings (same s, 4 ranges) share bid%8 -> same XCD -> re-read L2-served.
__global__ __launch_bounds__(TB) void range_accum(
        const unsigned short* __restrict__ li0h,
        const float* __restrict__ w,
        const int* __restrict__ row,
        const int* __restrict__ col,
        float* __restrict__ partial) {
    __shared__ unsigned short li0s[N_NODES];       // 100,000 B
    __shared__ float accl[RN];                     //  50,000 B  (total 150 KB)
    const int s  = blockIdx.x & (NSLICE - 1);
    const int r  = blockIdx.x >> 6;
    const int lo = r * RN;

    // coalesced LDS fill: 6250 uint4 = 100 KB
    {
        const uint4* srcv = (const uint4*)li0h;
        uint4* dstv = (uint4*)li0s;
        for (int i = threadIdx.x; i < N_NODES * 2 / 16; i += TB)
            dstv[i] = srcv[i];
    }
    float4* az = (float4*)accl;
    for (int i = threadIdx.x; i < RN / 4; i += TB)
        az[i] = make_float4(0.f, 0.f, 0.f, 0.f);
    __syncthreads();

    const float4* wq = (const float4*)w   + (size_t)s * SLICE_Q;
    const int4*   rq = (const int4*)row   + (size_t)s * SLICE_Q;
    const int4*   cq = (const int4*)col   + (size_t)s * SLICE_Q;

    for (int q = threadIdx.x; q < SLICE_Q; q += TB) {
        float4 wv = wq[q];
        int4   rv = rq[q];
        int4   cv = cq[q];
        // unconditional LDS gathers (cols always in-bounds, ~6cyc each)
        float g0 = bf2f(li0s[cv.x]);
        float g1 = bf2f(li0s[cv.y]);
        float g2 = bf2f(li0s[cv.z]);
        float g3 = bf2f(li0s[cv.w]);
        int a;
        a = rv.x - lo; if ((unsigned)a < RN) atomicAdd(&accl[a], wv.x * g0);
        a = rv.y - lo; if ((unsigned)a < RN) atomicAdd(&accl[a], wv.y * g1);
        a = rv.z - lo; if ((unsigned)a < RN) atomicAdd(&accl[a], wv.z * g2);
        a = rv.w - lo; if ((unsigned)a < RN) atomicAdd(&accl[a], wv.w * g3);
    }
    __syncthreads();

    float4* pdst = (float4*)(partial + (size_t)blockIdx.x * RN);
    for (int i = threadIdx.x; i < RN / 4; i += TB) pdst[i] = az[i];
}

// reduce: one node/thread, sum 64 slice-partials, relu, block-reduce,
// ticket-gated sigmoid finalize.
__global__ void reduce_fin(const float* __restrict__ partial,
                           float* __restrict__ sum,
                           unsigned* __restrict__ ticket,
                           float* __restrict__ out) {
    int n = blockIdx.x * blockDim.x + threadIdx.x;
    float local = 0.0f;
    if (n < N_NODES) {
        int rr = n / RN;
        int nl = n - rr * RN;
        const float* base = partial + (size_t)(rr * NSLICE) * RN + nl;
        float a0 = 0.f, a1 = 0.f, a2 = 0.f, a3 = 0.f;
        #pragma unroll 4
        for (int b = 0; b < NSLICE; b += 4) {
            a0 += base[(size_t)(b + 0) * RN];
            a1 += base[(size_t)(b + 1) * RN];
            a2 += base[(size_t)(b + 2) * RN];
            a3 += base[(size_t)(b + 3) * RN];
        }
        local = fmaxf(a0 + a1 + a2 + a3, 0.f);
    }
    #pragma unroll
    for (int off = 32; off > 0; off >>= 1)
        local += __shfl_down(local, off, 64);
    __shared__ float sm[4];
    if ((threadIdx.x & 63) == 0) sm[threadIdx.x >> 6] = local;
    __syncthreads();
    if (threadIdx.x == 0) {
        atomicAdd(sum, sm[0] + sm[1] + sm[2] + sm[3]);
        __threadfence();
        unsigned old = atomicAdd(ticket, 1u);
        if (old == gridDim.x - 1) {
            float v = __hip_atomic_load(sum, __ATOMIC_RELAXED, __HIP_MEMORY_SCOPE_AGENT);
            out[0] = 1.0f / (1.0f + expf(-v));
        }
    }
}

// ---------------- fallback (tiny ws): global atomics ----------------

__global__ void zero_acc(float* __restrict__ acc, float* sum, unsigned* ticket) {
    int i = blockIdx.x * blockDim.x + threadIdx.x;
    if (i < N_NODES) acc[i] = 0.0f;
    if (i == 0) { *sum = 0.0f; *ticket = 0u; }
}

__global__ void edge_scatter4(const float* __restrict__ li,
                              const float* __restrict__ w,
                              const int* __restrict__ row,
                              const int* __restrict__ col,
                              float* __restrict__ acc) {
    int t = blockIdx.x * blockDim.x + threadIdx.x;
    if (t < N_EDGES / 4) {
        float4 wv = ((const float4*)w)[t];
        int4   rv = ((const int4*)row)[t];
        int4   cv = ((const int4*)col)[t];
        atomicAdd(&acc[rv.x], wv.x * li[(size_t)cv.x * FEAT]);
        atomicAdd(&acc[rv.y], wv.y * li[(size_t)cv.y * FEAT]);
        atomicAdd(&acc[rv.z], wv.z * li[(size_t)cv.z * FEAT]);
        atomicAdd(&acc[rv.w], wv.w * li[(size_t)cv.w * FEAT]);
    }
}

__global__ void relu_sum_fin(const float* __restrict__ acc,
                             float* __restrict__ sum,
                             unsigned* __restrict__ ticket,
                             float* __restrict__ out) {
    float local = 0.0f;
    for (int i = blockIdx.x * blockDim.x + threadIdx.x; i < N_NODES / 4;
         i += gridDim.x * blockDim.x) {
        float4 a = ((const float4*)acc)[i];
        local += fmaxf(a.x, 0.f) + fmaxf(a.y, 0.f) +
                 fmaxf(a.z, 0.f) + fmaxf(a.w, 0.f);
    }
    #pragma unroll
    for (int off = 32; off > 0; off >>= 1)
        local += __shfl_down(local, off, 64);
    __shared__ float sm[4];
    if ((threadIdx.x & 63) == 0) sm[threadIdx.x >> 6] = local;
    __syncthreads();
    if (threadIdx.x == 0) {
        atomicAdd(sum, sm[0] + sm[1] + sm[2] + sm[3]);
        __threadfence();
        unsigned old = atomicAdd(ticket, 1u);
        if (old == gridDim.x - 1) {
            float v = __hip_atomic_load(sum, __ATOMIC_RELAXED, __HIP_MEMORY_SCOPE_AGENT);
            out[0] = 1.0f / (1.0f + expf(-v));
        }
    }
}

extern "C" void kernel_launch(void* const* d_in, const int* in_sizes, int n_in,
                              void* d_out, int out_size, void* d_ws, size_t ws_size,
                              hipStream_t stream) {
    const float* li  = (const float*)d_in[0];
    const float* w   = (const float*)d_in[1];
    const int*   row = (const int*)d_in[2];
    const int*   col = (const int*)d_in[3];
    float* out = (float*)d_out;

    size_t need = (size_t)NBLK * RN * 4 + (size_t)N_NODES * 2 + 16;

    if (ws_size >= need) {
        float*          partial = (float*)d_ws;
        unsigned short* li0h    = (unsigned short*)(partial + (size_t)NBLK * RN);
        float*          sum     = (float*)(li0h + N_NODES);
        unsigned*       ticket  = (unsigned*)(sum + 1);

        pack_init<<<(N_NODES + 255) / 256, 256, 0, stream>>>(li, li0h, sum, ticket);
        range_accum<<<NBLK, TB, 0, stream>>>(li0h, w, row, col, partial);
        reduce_fin<<<(N_NODES + 255) / 256, 256, 0, stream>>>(partial, sum, ticket, out);
    } else {
        float*    acc    = (float*)d_ws;
        float*    sum    = acc + N_NODES;
        unsigned* ticket = (unsigned*)(sum + 1);

        zero_acc<<<(N_NODES + 255) / 256, 256, 0, stream>>>(acc, sum, ticket);
        edge_scatter4<<<(N_EDGES / 4 + 255) / 256, 256, 0, stream>>>(li, w, row, col, acc);
        relu_sum_fin<<<49, 256, 0, stream>>>(acc, sum, ticket, out);
    }
}